// Round 5
// baseline (137.227 us; speedup 1.0000x reference)
//
#include <hip/hip_runtime.h>
#include <hip/hip_bf16.h>
#include <stdint.h>

// FGN layer: out = (x@W^T + bias) * exp(-( x^2@ic2^T + x@(-2c*ic2)^T + d ))
// R4 post-mortem: harness ws-poison fill = 41.7us fixed floor; gemm ~40us.
// Co-residency scaling: 1 blk/CU -> 45.4, 2 -> ~40. R5: 64Mx64N tiles,
// 1024 blocks = 4 independent blocks/CU (m97-class occupancy) so barrier
// drains of one block hide under MFMA of the other three.

typedef __attribute__((ext_vector_type(8))) __bf16 bf16x8;
typedef __attribute__((ext_vector_type(16))) float f32x16;

__device__ __forceinline__ unsigned short f2bf(float f) {
  union { float f; unsigned int u; } v; v.f = f;
  unsigned int u = v.u;
  unsigned int r = (u + 0x7FFFu + ((u >> 16) & 1u)) >> 16;  // RNE
  return (unsigned short)r;
}

// blocks 0..1023: 4096 O-rows (4/block, one wave each): W->bf16, ic2, -2c*ic2
// (bf16), bias/d reduced fp32. blocks 1024..1279: x->bf16.
__global__ __launch_bounds__(256) void prep(
    const float* __restrict__ X, const float* __restrict__ W,
    const float* __restrict__ C, const float* __restrict__ IC,
    unsigned short* __restrict__ Wb, unsigned short* __restrict__ I2b,
    unsigned short* __restrict__ M2b, unsigned short* __restrict__ Xb,
    float* __restrict__ bias, float* __restrict__ dvec) {
  const int b = blockIdx.x;
  if (b < 1024) {
    const int wave = threadIdx.x >> 6;
    const int lane = threadIdx.x & 63;
    const int row  = b * 4 + wave;
    const float4* W4 = (const float4*)W + (size_t)row * 256;
    const float4* C4 = (const float4*)C + (size_t)row * 256;
    const float4* I4 = (const float4*)IC + (size_t)row * 256;
    ushort4* Wo = (ushort4*)Wb + (size_t)row * 256;
    ushort4* Io = (ushort4*)I2b + (size_t)row * 256;
    ushort4* Mo = (ushort4*)M2b + (size_t)row * 256;
    float swc = 0.f, sd = 0.f;
#pragma unroll
    for (int p = 0; p < 4; ++p) {
      int idx = lane + p * 64;
      float4 w = W4[idx], c = C4[idx], ic = I4[idx];
      float i2x = ic.x * ic.x, i2y = ic.y * ic.y, i2z = ic.z * ic.z, i2w = ic.w * ic.w;
      swc += w.x * c.x + w.y * c.y + w.z * c.z + w.w * c.w;
      sd  += c.x * c.x * i2x + c.y * c.y * i2y + c.z * c.z * i2z + c.w * c.w * i2w;
      ushort4 a, bb, m;
      a.x = f2bf(w.x); a.y = f2bf(w.y); a.z = f2bf(w.z); a.w = f2bf(w.w);
      bb.x = f2bf(i2x); bb.y = f2bf(i2y); bb.z = f2bf(i2z); bb.w = f2bf(i2w);
      m.x = f2bf(-2.f * c.x * i2x); m.y = f2bf(-2.f * c.y * i2y);
      m.z = f2bf(-2.f * c.z * i2z); m.w = f2bf(-2.f * c.w * i2w);
      Wo[idx] = a; Io[idx] = bb; Mo[idx] = m;
    }
#pragma unroll
    for (int off = 32; off > 0; off >>= 1) {
      swc += __shfl_down(swc, off);
      sd  += __shfl_down(sd, off);
    }
    if (lane == 0) { bias[row] = -swc; dvec[row] = sd; }
  } else {
    const int xb = b - 1024;  // 0..255
#pragma unroll
    for (int j = 0; j < 4; ++j) {
      int idx = xb * 1024 + j * 256 + threadIdx.x;
      float4 v = ((const float4*)X)[idx];
      ushort4 a;
      a.x = f2bf(v.x); a.y = f2bf(v.y); a.z = f2bf(v.z); a.w = f2bf(v.w);
      ((ushort4*)Xb)[idx] = a;
    }
  }
}

#define GLD16(gp, lp)                                                          \
  __builtin_amdgcn_global_load_lds(                                            \
      (const __attribute__((address_space(1))) unsigned int*)(gp),             \
      (__attribute__((address_space(3))) unsigned int*)(lp), 16, 0, 0)

// 64M x 64N block tile, BK=32, 256 threads = 4 waves: kg = wave>>1 picks the
// MFMA k-step (0/1), wq = wave&1 picks the 32-wide N strip. Wave tile 64Mx32N
// = 2 m-frags of 32x32x16. kg=1 partials reduced into kg=0 via LDS epilogue.
// LDS: 2 bufs x 4 streams x 4 KB = 32 KB -> 4 blocks/CU co-resident.
// XOR swizzle slot ^= (row>>1)&3 for conflict-free b128 reads.
// Grid (64 n, 16 m) = 1024 blocks = 4/CU; XCD = n%8 -> B-panel L2 reuse.
__global__ __launch_bounds__(256, 4) void fgn_gemm(
    const unsigned short* __restrict__ Xb, const unsigned short* __restrict__ Wb,
    const unsigned short* __restrict__ I2b, const unsigned short* __restrict__ M2b,
    const float* __restrict__ bias, const float* __restrict__ dvec,
    float* __restrict__ out) {
  __shared__ unsigned char smem[32768];
#define SBUF(B, S) ((unsigned short*)(smem + (B) * 16384 + (S) * 4096))
  const int t = threadIdx.x;
  const int m0 = blockIdx.y * 64;
  const int n0 = blockIdx.x * 64;

  // staging: 256 chunks of 16B per stream per slab = exactly 1/thread.
  // chunk t -> LDS row t>>2, slot t&3; global k-chunk = slot ^ ((row>>1)&3).
  const int srow = t >> 2;
  const int gco  = ((t & 3) ^ ((srow >> 1) & 3)) * 8;
  const unsigned short* gx = Xb  + (size_t)(m0 + srow) * 1024 + gco;
  const unsigned short* gw = Wb  + (size_t)(n0 + srow) * 1024 + gco;
  const unsigned short* gi = I2b + (size_t)(n0 + srow) * 1024 + gco;
  const unsigned short* gm = M2b + (size_t)(n0 + srow) * 1024 + gco;

#define STAGE(B, KO)                                                           \
  do {                                                                         \
    GLD16(gx + (KO), SBUF(B, 0) + t * 8);                                      \
    GLD16(gw + (KO), SBUF(B, 1) + t * 8);                                      \
    GLD16(gi + (KO), SBUF(B, 2) + t * 8);                                      \
    GLD16(gm + (KO), SBUF(B, 3) + t * 8);                                      \
  } while (0)

  const int wave = t >> 6;
  const int kg = wave >> 1;        // k-step group
  const int wq = wave & 1;         // N strip
  const int lane = t & 63;
  const int ln = lane & 31, kh = lane >> 5;
  const int co = (((kg << 1) | kh) ^ ((ln >> 1) & 3)) * 8;

  int aoff[2];
#pragma unroll
  for (int mt = 0; mt < 2; ++mt) aoff[mt] = (mt * 32 + ln) * 32 + co;
  const int boff = (wq * 32 + ln) * 32 + co;

  f32x16 accL[2], accG[2];
#pragma unroll
  for (int mt = 0; mt < 2; ++mt) { accL[mt] = (f32x16)0.f; accG[mt] = (f32x16)0.f; }

#define COMPUTE(B)                                                             \
  do {                                                                         \
    const unsigned short* px = SBUF(B, 0);                                     \
    bf16x8 ax[2], aq[2];                                                       \
    _Pragma("unroll")                                                          \
    for (int mt = 0; mt < 2; ++mt) ax[mt] = *(const bf16x8*)(px + aoff[mt]);   \
    bf16x8 bw = *(const bf16x8*)(SBUF(B, 1) + boff);                           \
    bf16x8 bi = *(const bf16x8*)(SBUF(B, 2) + boff);                           \
    bf16x8 bm = *(const bf16x8*)(SBUF(B, 3) + boff);                           \
    _Pragma("unroll")                                                          \
    for (int mt = 0; mt < 2; ++mt) {                                           \
      bf16x8 a = ax[mt], q;                                                    \
      _Pragma("unroll")                                                        \
      for (int j = 0; j < 8; ++j) { float f = (float)a[j]; q[j] = (__bf16)(f * f); } \
      aq[mt] = q;                                                              \
    }                                                                          \
    _Pragma("unroll")                                                          \
    for (int mt = 0; mt < 2; ++mt)                                             \
      accL[mt] = __builtin_amdgcn_mfma_f32_32x32x16_bf16(ax[mt], bw, accL[mt], 0, 0, 0); \
    _Pragma("unroll")                                                          \
    for (int mt = 0; mt < 2; ++mt)                                             \
      accG[mt] = __builtin_amdgcn_mfma_f32_32x32x16_bf16(aq[mt], bi, accG[mt], 0, 0, 0); \
    _Pragma("unroll")                                                          \
    for (int mt = 0; mt < 2; ++mt)                                             \
      accG[mt] = __builtin_amdgcn_mfma_f32_32x32x16_bf16(ax[mt], bm, accG[mt], 0, 0, 0); \
  } while (0)

  STAGE(0, 0);
  __syncthreads();
#pragma unroll 1
  for (int p = 0; p < 32; p += 2) {
    STAGE(1, (p + 1) * 32);            // prefetch next slab into other buffer
    COMPUTE(0);
    __syncthreads();
    if (p + 2 < 32) STAGE(0, (p + 2) * 32);
    COMPUTE(1);
    __syncthreads();
  }

  // ---- epilogue: reduce kg=1 partials into kg=0, apply bias/exp, store ----
  const int col = n0 + wq * 32 + ln;
  float bn = 0.f, dn = 0.f;
  if (kg == 0) { bn = bias[col]; dn = dvec[col]; }
  {
    float* base = (float*)(smem + wq * 8192 + lane * 64);  // +mt*4096
    // round 1: accL
    if (kg == 1) {
#pragma unroll
      for (int mt = 0; mt < 2; ++mt) *(f32x16*)(base + mt * 1024) = accL[mt];
    }
    __syncthreads();
    if (kg == 0) {
#pragma unroll
      for (int mt = 0; mt < 2; ++mt) accL[mt] += *(const f32x16*)(base + mt * 1024);
    }
    __syncthreads();
    // round 2: accG
    if (kg == 1) {
#pragma unroll
      for (int mt = 0; mt < 2; ++mt) *(f32x16*)(base + mt * 1024) = accG[mt];
    }
    __syncthreads();
    if (kg == 0) {
#pragma unroll
      for (int mt = 0; mt < 2; ++mt) {
        accG[mt] += *(const f32x16*)(base + mt * 1024);
        // C/D 32x32 layout: col=lane&31, row=(reg&3)+8*(reg>>2)+4*(lane>>5)
        int rb = m0 + mt * 32 + 4 * kh;
#pragma unroll
        for (int r = 0; r < 16; ++r) {
          int row = rb + (r & 3) + 8 * (r >> 2);
          float l = accL[mt][r] + bn;
          float g = accG[mt][r] + dn;
          out[(size_t)row * 4096 + col] = l * __expf(-g);
        }
      }
    }
  }
#undef STAGE
#undef COMPUTE
#undef SBUF
}

extern "C" void kernel_launch(void* const* d_in, const int* in_sizes, int n_in,
                              void* d_out, int out_size, void* d_ws, size_t ws_size,
                              hipStream_t stream) {
  const float* x  = (const float*)d_in[0];
  const float* W  = (const float*)d_in[1];
  const float* C  = (const float*)d_in[2];
  const float* IC = (const float*)d_in[3];
  float* out = (float*)d_out;

  char* ws = (char*)d_ws;
  unsigned short* Wb  = (unsigned short*)(ws);                          // 8 MB
  unsigned short* I2b = (unsigned short*)(ws + (8u << 20));             // 8 MB
  unsigned short* M2b = (unsigned short*)(ws + (16u << 20));            // 8 MB
  unsigned short* Xb  = (unsigned short*)(ws + (24u << 20));            // 2 MB
  float* bias = (float*)(ws + (26u << 20));                             // 16 KB
  float* dvec = (float*)(ws + (26u << 20) + 16384);                     // 16 KB

  hipLaunchKernelGGL(prep, dim3(1280), dim3(256), 0, stream, x, W, C, IC,
                     Wb, I2b, M2b, Xb, bias, dvec);
  hipLaunchKernelGGL(fgn_gemm, dim3(64, 16), dim3(256), 0, stream,
                     Xb, Wb, I2b, M2b, bias, dvec, out);
}

// Round 6
// 128.533 us; speedup vs baseline: 1.0676x; 1.0676x over previous
//
#include <hip/hip_runtime.h>
#include <hip/hip_bf16.h>
#include <stdint.h>

// FGN layer: out = (x@W^T + bias) * exp(-( x^2@ic2^T + x@(-2c*ic2)^T + d ))
// R5 post-mortem: MfmaUtil pinned at 21% across 5 structures = per-slab
// vmcnt(0)-before-barrier drain serializes everything; extra waves don't
// help. R6: (1) triple-buffer distance-2 prefetch with manual
// s_waitcnt vmcnt(6) + raw s_barrier (never full drain mid-loop);
// (2) G-GEMM entirely in fp8 e4m3 (scale 2^23 folded into ic2'/m2',
// undone in epilogue) -> fewer LDS bytes, no x^2 VALU;
// (3) R4's best shape: 128Mx64N, 512 blocks = 2/CU, 4 waves 2m x 2n.

typedef __attribute__((ext_vector_type(8))) __bf16 bf16x8;
typedef __attribute__((ext_vector_type(16))) float f32x16;

#define G_SCALE 8388608.0f   /* 2^23 */
#define G_INV   1.1920929e-7f /* 2^-23 */

__device__ __forceinline__ unsigned short f2bf(float f) {
  union { float f; unsigned int u; } v; v.f = f;
  unsigned int u = v.u;
  return (unsigned short)((u + 0x7FFFu + ((u >> 16) & 1u)) >> 16);  // RNE
}

// fp8 e4m3fn encode, RNE, flush-to-zero below 2^-6 (values there are
// numerically irrelevant for G: delta_g < 1e-7).
__device__ __forceinline__ unsigned int f2f8(float f) {
  union { float f; unsigned int u; } v; v.f = f;
  unsigned int u = v.u;
  unsigned int s = (u >> 31) << 7;
  unsigned int e = (u >> 23) & 255u;
  if (e < 121u) return s;                      // |f| < 2^-6 -> 0
  unsigned int q = ((e - 120u) << 23) | (u & 0x7FFFFFu);
  unsigned int r = (q + 0x7FFFFu + ((q >> 20) & 1u)) >> 20;
  if (r > 126u) r = 126u;                      // clamp to 448
  return s | r;
}

__device__ __forceinline__ unsigned long long pack8f8(const float* x) {
  unsigned long long r = 0;
#pragma unroll
  for (int j = 0; j < 8; ++j) r |= (unsigned long long)f2f8(x[j]) << (8 * j);
  return r;
}

// blocks 0..1023: one wave per O-row (4 rows/block): Wb = bf16(W) row-major;
// GBb packed per row: for each 8-k group g: [fp8(ic2*2^23) 8B | fp8(-2c*ic2*2^23) 8B];
// bias_i = -sum W*C, d_i = sum C^2*ic2 in fp32.
// blocks 1024..1279: 4 x-rows/block: Xb = bf16(x) row-major; XQb packed:
// per 8-k group: [fp8(x^2) 8B | fp8(x) 8B].
__global__ __launch_bounds__(256) void prep(
    const float* __restrict__ X, const float* __restrict__ W,
    const float* __restrict__ C, const float* __restrict__ IC,
    unsigned short* __restrict__ Wb, char* __restrict__ GBb,
    unsigned short* __restrict__ Xb, char* __restrict__ XQb,
    float* __restrict__ bias, float* __restrict__ dvec) {
  const int b = blockIdx.x;
  const int lane = threadIdx.x & 63;
  if (b < 1024) {
    const int row = b * 4 + (threadIdx.x >> 6);
    const float4* W4 = (const float4*)W + (size_t)row * 256 + lane * 4;
    const float4* C4 = (const float4*)C + (size_t)row * 256 + lane * 4;
    const float4* I4 = (const float4*)IC + (size_t)row * 256 + lane * 4;
    float wv[16], cv[16], i2[16], m2[16], i2s[16];
    float swc = 0.f, sd = 0.f;
#pragma unroll
    for (int p = 0; p < 4; ++p) {
      float4 w = W4[p], c = C4[p], ic = I4[p];
      wv[4*p] = w.x; wv[4*p+1] = w.y; wv[4*p+2] = w.z; wv[4*p+3] = w.w;
      cv[4*p] = c.x; cv[4*p+1] = c.y; cv[4*p+2] = c.z; cv[4*p+3] = c.w;
      i2[4*p] = ic.x*ic.x; i2[4*p+1] = ic.y*ic.y; i2[4*p+2] = ic.z*ic.z; i2[4*p+3] = ic.w*ic.w;
    }
#pragma unroll
    for (int j = 0; j < 16; ++j) {
      swc += wv[j] * cv[j];
      sd  += cv[j] * cv[j] * i2[j];
      i2s[j] = i2[j] * G_SCALE;
      m2[j]  = -2.f * cv[j] * i2[j] * G_SCALE;
    }
    ushort4* Wo = (ushort4*)Wb + (size_t)row * 256 + lane * 4;
#pragma unroll
    for (int p = 0; p < 4; ++p) {
      ushort4 a;
      a.x = f2bf(wv[4*p]); a.y = f2bf(wv[4*p+1]);
      a.z = f2bf(wv[4*p+2]); a.w = f2bf(wv[4*p+3]);
      Wo[p] = a;
    }
    ulonglong2* gb = (ulonglong2*)(GBb + (size_t)row * 2048 + lane * 32);
    ulonglong2 u0, u1;
    u0.x = pack8f8(i2s);     u0.y = pack8f8(m2);
    u1.x = pack8f8(i2s + 8); u1.y = pack8f8(m2 + 8);
    gb[0] = u0; gb[1] = u1;
#pragma unroll
    for (int off = 32; off > 0; off >>= 1) {
      swc += __shfl_down(swc, off);
      sd  += __shfl_down(sd, off);
    }
    if (lane == 0) { bias[row] = -swc; dvec[row] = sd; }
  } else {
    const int row = (b - 1024) * 4 + (threadIdx.x >> 6);
    const float4* X4 = (const float4*)X + (size_t)row * 256 + lane * 4;
    float xv[16], qv[16];
#pragma unroll
    for (int p = 0; p < 4; ++p) {
      float4 x = X4[p];
      xv[4*p] = x.x; xv[4*p+1] = x.y; xv[4*p+2] = x.z; xv[4*p+3] = x.w;
    }
#pragma unroll
    for (int j = 0; j < 16; ++j) qv[j] = xv[j] * xv[j];
    ushort4* Xo = (ushort4*)Xb + (size_t)row * 256 + lane * 4;
#pragma unroll
    for (int p = 0; p < 4; ++p) {
      ushort4 a;
      a.x = f2bf(xv[4*p]); a.y = f2bf(xv[4*p+1]);
      a.z = f2bf(xv[4*p+2]); a.w = f2bf(xv[4*p+3]);
      Xo[p] = a;
    }
    ulonglong2* xq = (ulonglong2*)(XQb + (size_t)row * 2048 + lane * 32);
    ulonglong2 u0, u1;
    u0.x = pack8f8(qv);     u0.y = pack8f8(xv);
    u1.x = pack8f8(qv + 8); u1.y = pack8f8(xv + 8);
    xq[0] = u0; xq[1] = u1;
  }
}

#define GLD16(gp, lp)                                                          \
  __builtin_amdgcn_global_load_lds(                                            \
      (const __attribute__((address_space(1))) unsigned int*)(gp),             \
      (__attribute__((address_space(3))) unsigned int*)(lp), 16, 0, 0)

// 128M x 64N tile, BK=32, 256 thr = 4 waves (wy m-half, wx n-half), wave tile
// 64Mx32N = 2 m-frags of 32x32x16. Triple-buffered LDS (3 x 24 KB), prefetch
// distance 2, manual s_waitcnt vmcnt(6)+s_barrier per slab (6 GLD16/thread
// per STAGE -> vmcnt(6) waits exactly the slab staged 2 iters ago).
// All streams 2 KB/row; 16B chunks staged with XOR swizzle slot^((row>>1)&3)
// -> conflict-free b128 fragment reads. Grid (64 n, 8 m) = 512 = 2/CU;
// same-n blocks share an XCD (W/GB panel 256 KB hot in XCD L2).
__global__ __launch_bounds__(256, 2) void fgn_gemm(
    const char* __restrict__ Xb, const char* __restrict__ XQb,
    const char* __restrict__ Wb, const char* __restrict__ GBb,
    const float* __restrict__ bias, const float* __restrict__ dvec,
    float* __restrict__ out) {
  __shared__ char smem[73728];                 // 3 x 24 KB
  const int t = threadIdx.x;
  const int m0 = blockIdx.y * 128;
  const int n0 = blockIdx.x * 64;

  const int srow = t >> 2;
  const int gof = ((t & 3) ^ ((srow >> 1) & 3)) * 16;
  const char* gX  = Xb  + (size_t)(m0 + srow) * 2048 + gof;
  const char* gXQ = XQb + (size_t)(m0 + srow) * 2048 + gof;
  const char* gW  = Wb  + (size_t)(n0 + srow) * 2048 + gof;
  const char* gGB = GBb + (size_t)(n0 + srow) * 2048 + gof;

  // LDS buffer layout (24 KB): X 0..8K (128 rows x 64B), XQ 8K..16K,
  // W 16K..20K (64 rows x 64B), GB 20K..24K.
#define LBASE(B) (smem + (size_t)(B) * 24576)
#define STAGE(B, S)                                                            \
  do {                                                                         \
    const int ko = (S) * 64;                                                   \
    char* lb = LBASE(B);                                                       \
    GLD16(gX + ko,           lb + t * 16);                                     \
    GLD16(gX + ko + 131072,  lb + 4096 + t * 16);                              \
    GLD16(gXQ + ko,          lb + 8192 + t * 16);                              \
    GLD16(gXQ + ko + 131072, lb + 12288 + t * 16);                             \
    GLD16(gW + ko,           lb + 16384 + t * 16);                             \
    GLD16(gGB + ko,          lb + 20480 + t * 16);                             \
  } while (0)

  const int wave = t >> 6, lane = t & 63;
  const int wy = wave >> 1, wx = wave & 1;
  const int ln = lane & 31, kh = lane >> 5;
  const int sw = (ln >> 1) & 3;

  int arow[2];
#pragma unroll
  for (int mt = 0; mt < 2; ++mt) arow[mt] = (wy * 64 + mt * 32 + ln) * 64;
  const int brow = (wx * 32 + ln) * 64;

  f32x16 accL[2], accG[2];
#pragma unroll
  for (int mt = 0; mt < 2; ++mt) { accL[mt] = (f32x16)0.f; accG[mt] = (f32x16)0.f; }

#define COMPUTE(B)                                                             \
  do {                                                                         \
    char* lb = LBASE(B);                                                       \
    _Pragma("unroll")                                                          \
    for (int ks = 0; ks < 2; ++ks) {                                           \
      const int u16 = ((2 * ks + kh) ^ sw) * 16;                               \
      bf16x8 ax0 = *(const bf16x8*)(lb + arow[0] + u16);                       \
      bf16x8 ax1 = *(const bf16x8*)(lb + arow[1] + u16);                       \
      long2 xq0 = *(const long2*)(lb + 8192 + arow[0] + u16);                  \
      long2 xq1 = *(const long2*)(lb + 8192 + arow[1] + u16);                  \
      bf16x8 bw = *(const bf16x8*)(lb + 16384 + brow + u16);                   \
      long2 gb  = *(const long2*)(lb + 20480 + brow + u16);                    \
      accL[0] = __builtin_amdgcn_mfma_f32_32x32x16_bf16(ax0, bw, accL[0], 0, 0, 0); \
      accL[1] = __builtin_amdgcn_mfma_f32_32x32x16_bf16(ax1, bw, accL[1], 0, 0, 0); \
      accG[0] = __builtin_amdgcn_mfma_f32_32x32x16_fp8_fp8(xq0.x, gb.x, accG[0], 0, 0, 0); \
      accG[1] = __builtin_amdgcn_mfma_f32_32x32x16_fp8_fp8(xq1.x, gb.x, accG[1], 0, 0, 0); \
      accG[0] = __builtin_amdgcn_mfma_f32_32x32x16_fp8_fp8(xq0.y, gb.y, accG[0], 0, 0, 0); \
      accG[1] = __builtin_amdgcn_mfma_f32_32x32x16_fp8_fp8(xq1.y, gb.y, accG[1], 0, 0, 0); \
    }                                                                          \
  } while (0)

  STAGE(0, 0);
  STAGE(1, 1);
#pragma unroll 1
  for (int s = 0; s < 31; ++s) {
    // vmcnt(6): wait for all but the newest STAGE (6 loads) -> the buffer
    // we are about to read (staged 2 slabs ago) is landed; the distance-1
    // prefetch stays in flight across the barrier. lgkmcnt(0): our ds_reads
    // of the previous slab are complete. expcnt=7 (no wait).
    __builtin_amdgcn_s_waitcnt(0x0076);
    __builtin_amdgcn_s_barrier();
    COMPUTE(s % 3);
    if (s < 30) STAGE((s + 2) % 3, s + 2);
  }
  __builtin_amdgcn_s_waitcnt(0x0070);   // last slab: full vmcnt drain
  __builtin_amdgcn_s_barrier();
  COMPUTE(31 % 3);

  // epilogue: direct store, no inter-wave reduction.
  // C/D 32x32 layout: col=lane&31, row=(reg&3)+8*(reg>>2)+4*(lane>>5)
  const int col = n0 + wx * 32 + ln;
  const float bn = bias[col], dn = dvec[col];
#pragma unroll
  for (int mt = 0; mt < 2; ++mt) {
    const int rb = m0 + wy * 64 + mt * 32 + 4 * kh;
#pragma unroll
    for (int r = 0; r < 16; ++r) {
      const int row = rb + (r & 3) + 8 * (r >> 2);
      const float l = accL[mt][r] + bn;
      const float g = accG[mt][r] * G_INV + dn;
      out[(size_t)row * 4096 + col] = l * __expf(-g);
    }
  }
#undef STAGE
#undef COMPUTE
#undef LBASE
}

extern "C" void kernel_launch(void* const* d_in, const int* in_sizes, int n_in,
                              void* d_out, int out_size, void* d_ws, size_t ws_size,
                              hipStream_t stream) {
  const float* x  = (const float*)d_in[0];
  const float* W  = (const float*)d_in[1];
  const float* C  = (const float*)d_in[2];
  const float* IC = (const float*)d_in[3];
  float* out = (float*)d_out;

  char* ws = (char*)d_ws;
  unsigned short* Wb  = (unsigned short*)(ws);                 // 8 MB bf16 W
  char*           GBb = ws + (8u << 20);                       // 8 MB [ic2'|m2'] fp8
  unsigned short* Xb  = (unsigned short*)(ws + (16u << 20));   // 2 MB bf16 x
  char*           XQb = ws + (18u << 20);                      // 2 MB [q|xf] fp8
  float* bias = (float*)(ws + (20u << 20));                    // 16 KB
  float* dvec = (float*)(ws + (20u << 20) + 16384);            // 16 KB

  hipLaunchKernelGGL(prep, dim3(1280), dim3(256), 0, stream, x, W, C, IC,
                     Wb, GBb, Xb, XQb, bias, dvec);
  hipLaunchKernelGGL(fgn_gemm, dim3(64, 8), dim3(256), 0, stream,
                     Xb ? (const char*)Xb : nullptr, XQb,
                     (const char*)Wb, GBb, bias, dvec, out);
}